// Round 7
// baseline (192.359 us; speedup 1.0000x reference)
//
#include <hip/hip_runtime.h>
#include <math.h>

// Nq=20000, K=32, Cin=3, Fc=64, Co=64.
// Producer/consumer wave specialization, double-buffered LDS, 1 barrier/iter:
//   waves 0-1: gather + logits + softmax + xv for pair p+1  -> buf^1
//   waves 2-3: MFMA (attn@Wa, yg@Wr) + epilogue + k-max for pair p <- buf
#define KNB 32
#define FC 64
#define CO 64
#define EPS 1e-5f
#define NBLOCKS 768
#define CL 0.180336880095853f   // 0.125 * log2(e): softmax scale folded for exp2

typedef __attribute__((ext_vector_type(8))) short short8;   // 8 bf16 = 4 VGPRs
typedef __attribute__((ext_vector_type(4))) float floatx4;  // MFMA C/D

#if __has_builtin(__builtin_amdgcn_exp2f)
#define EXP2F(x) __builtin_amdgcn_exp2f(x)
#else
#define EXP2F(x) exp2f(x)
#endif
#if __has_builtin(__builtin_amdgcn_rcpf)
#define RCPF(x) __builtin_amdgcn_rcpf(x)
#else
#define RCPF(x) (1.f / (x))
#endif

// round-to-nearest (ties away) f32->bf16; 5x error-budget headroom vs RNE.
__device__ __forceinline__ unsigned int pkbf(float a, float b) {  // a->lo, b->hi
    unsigned int ua = (__float_as_uint(a) + 0x8000u) >> 16;
    unsigned int ub = (__float_as_uint(b) + 0x8000u) & 0xFFFF0000u;
    return ua | ub;                 // v_and_or_b32
}
__device__ __forceinline__ short f2bf(float x) {
    return (short)((__float_as_uint(x) + 0x8000u) >> 16);
}
__device__ __forceinline__ float lrelu(float x) { return fmaxf(x, 0.1f * x); }

// (256,3): 170-VGPR budget -> no spill (r4: (256,6) spilled, 2x regression).
__global__ __launch_bounds__(256, 3) void GCT_61272003445298_kernel(
    const float* __restrict__ q_points,   // [Nq,3]
    const float* __restrict__ s_points,   // [Nq,3]
    const int*   __restrict__ neighb,     // [Nq,32]
    const float* __restrict__ feat,       // [Nq,64]
    const float* __restrict__ W_pos2,     // [64,3]
    const float* __restrict__ W_attn,     // [192,64]
    const float* __restrict__ W_res,      // [64,64]
    const float* __restrict__ bnq_g, const float* __restrict__ bnq_b,
    const float* __restrict__ bnq_m, const float* __restrict__ bnq_v,
    const float* __restrict__ bnp_g, const float* __restrict__ bnp_b,
    const float* __restrict__ bnp_m, const float* __restrict__ bnp_v,
    const float* __restrict__ bn1_g, const float* __restrict__ bn1_b,
    const float* __restrict__ bn1_m, const float* __restrict__ bn1_v,
    const float* __restrict__ bnr_g, const float* __restrict__ bnr_b,
    const float* __restrict__ bnr_m, const float* __restrict__ bnr_v,
    const float* __restrict__ zp,         // 4KB zero page in d_ws (shadow row)
    float* __restrict__ out, int Nq)
{
    const int t = threadIdx.x;
    const int wv = t >> 6;
    const int lane = t & 63;
    const int bid = blockIdx.x;

    // rows: m = q*32 + k; pitch 72 shorts = 144 B, 16B-aligned b128 access
    __shared__ __align__(16) short sA1[2][64 * 72];   // softmax probs, bf16
    __shared__ __align__(16) short sA2[2][64 * 72];   // gathered yg, bf16
    __shared__ __align__(16) float sXv[2][64][4];     // x_v per row
    __shared__ __align__(16) float sWp2[192];         // CL * W_pos2
    __shared__ __align__(16) float sQs[64], sQb[64];  // bnq folded

    // ---------------- one-time init (all threads) ----------------
    if (t < 192) sWp2[t] = CL * W_pos2[t];
    if (t < 64) {
        float sc = bnq_g[t] * rsqrtf(bnq_v[t] + EPS);
        sQs[t] = sc; sQb[t] = bnq_b[t] - bnq_m[t] * sc;
    }
    // bnp folded (uniform -> scalar regs)
    const float ps0 = bnp_g[0] * rsqrtf(bnp_v[0] + EPS);
    const float ps1 = bnp_g[1] * rsqrtf(bnp_v[1] + EPS);
    const float ps2 = bnp_g[2] * rsqrtf(bnp_v[2] + EPS);
    const float pb0 = bnp_b[0] - bnp_m[0] * ps0;
    const float pb1 = bnp_b[1] - bnp_m[1] * ps1;
    const float pb2 = bnp_b[2] - bnp_m[2] * ps2;
    __syncthreads();

    const bool producer = (wv < 2);
    const int npair = (Nq + 1) >> 1;
    const int niter = (npair - bid + NBLOCKS - 1) / NBLOCKS;   // block-uniform

    // ---- producer persistent: thread = (qB, kg, fi) = wave, k-group, f-chunk ----
    const int qB = __builtin_amdgcn_readfirstlane(wv & 1);     // wave-uniform
    const int kg = lane >> 3;           // 0..7 -> rows kg*4..+3
    const int fi = lane & 7;            // 0..7 -> f = fi*8..+7
    float wp[24];                       // CL*W_pos2 rows for this thread's 8 f
    // ---- consumer persistent: wave cwv owns cols cwv*32..+31 as 2 groups ----
    const int cc = lane & 15, quad = lane >> 4;
    short8 bW[2][4][2];                 // [group][type 3xWa+Wr][k-slice]
    float e1s[2], e1b[2], ers[2], erb[2];

    if (producer) {
        #pragma unroll
        for (int v = 0; v < 6; ++v)
            *(float4*)&wp[v * 4] = *(const float4*)&sWp2[fi * 24 + v * 4];
    } else {
        const int cwv = wv - 2;
        #pragma unroll
        for (int g = 0; g < 2; ++g) {
            const int o = cwv * 32 + g * 16 + cc;
            float s1v = bn1_g[o] * rsqrtf(bn1_v[o] + EPS);
            e1s[g] = s1v; e1b[g] = bn1_b[o] - bn1_m[o] * s1v;
            float srv = bnr_g[o] * rsqrtf(bnr_v[o] + EPS);
            ers[g] = srv; erb[g] = bnr_b[o] - bnr_m[o] * srv;
            #pragma unroll
            for (int ty = 0; ty < 4; ++ty) {
                const float* wrow = (ty < 3) ? (W_attn + (long)(o * 3 + ty) * FC)
                                             : (W_res  + (long)o * FC);
                #pragma unroll
                for (int ks = 0; ks < 2; ++ks) {
                    int k0 = ks * 32 + quad * 8;
                    float4 w0 = *(const float4*)(wrow + k0);
                    float4 w1 = *(const float4*)(wrow + k0 + 4);
                    short8 bb;
                    bb[0] = f2bf(w0.x); bb[1] = f2bf(w0.y); bb[2] = f2bf(w0.z); bb[3] = f2bf(w0.w);
                    bb[4] = f2bf(w1.x); bb[5] = f2bf(w1.y); bb[6] = f2bf(w1.z); bb[7] = f2bf(w1.w);
                    bW[g][ty][ks] = bb;
                }
            }
        }
    }

    // ---------------- producer: fill one pair into buffer b ----------------
    auto produce = [&](int pr, int b) {
        int nn = 2 * pr + qB;
        if (nn >= Nq) nn = 2 * pr;                 // odd-Nq guard (Nq even here)
        const float* qp  = q_points + (long)nn * 3;
        const float q0 = qp[0], q1 = qp[1], q2 = qp[2];
        const float* spn = s_points + (long)nn * 3;
        const float pp0 = lrelu(fmaf(spn[0], ps0, pb0));
        const float pp1 = lrelu(fmaf(spn[1], ps1, pb1));
        const float pp2 = lrelu(fmaf(spn[2], ps2, pb2));
        const int4 idx4 = *(const int4*)(neighb + (long)nn * KNB + kg * 4);

        // xqc[c] = CL*xq + pos0 . wp  (redundant x8 kg lanes)
        float xqc[8];
        {
            const float4 fxa = *(const float4*)(feat + (long)nn * FC + fi * 8);
            const float4 fxb = *(const float4*)(feat + (long)nn * FC + fi * 8 + 4);
            const float4 qsa = *(const float4*)&sQs[fi * 8];
            const float4 qsb = *(const float4*)&sQs[fi * 8 + 4];
            const float4 qba = *(const float4*)&sQb[fi * 8];
            const float4 qbb = *(const float4*)&sQb[fi * 8 + 4];
            const float fx[8] = {fxa.x, fxa.y, fxa.z, fxa.w, fxb.x, fxb.y, fxb.z, fxb.w};
            const float qs[8] = {qsa.x, qsa.y, qsa.z, qsa.w, qsb.x, qsb.y, qsb.z, qsb.w};
            const float qb[8] = {qba.x, qba.y, qba.z, qba.w, qbb.x, qbb.y, qbb.z, qbb.w};
            #pragma unroll
            for (int c = 0; c < 8; ++c) {
                float xq = lrelu(fmaf(fx[c], qs[c], qb[c]));
                xqc[c] = fmaf(pp0, wp[c*3], fmaf(pp1, wp[c*3+1], fmaf(pp2, wp[c*3+2], CL * xq)));
            }
        }

        short* a1b = &sA1[b][(qB * 32 + kg * 4) * 72 + fi * 8];
        short* a2b = &sA2[b][(qB * 32 + kg * 4) * 72 + fi * 8];
        float ev[4][8];
        float sm[8] = {0.f, 0.f, 0.f, 0.f, 0.f, 0.f, 0.f, 0.f};
        #pragma unroll
        for (int j = 0; j < 4; ++j) {
            const int idx = ((const int*)&idx4)[j];
            const bool valid = (idx < Nq);          // idx==Nq -> shadow zero row
            const float* fb = valid ? (feat + (long)idx * FC) : zp;
            const float* sb = valid ? (s_points + (long)idx * 3) : zp;
            const float4 ya = *(const float4*)(fb + fi * 8);
            const float4 yb = *(const float4*)(fb + fi * 8 + 4);
            const float xv0 = sb[0] - q0;
            const float xv1 = sb[1] - q1;
            const float xv2 = sb[2] - q2;
            if (fi == 0) {
                float4 xvv = {xv0, xv1, xv2, 0.f};
                *(float4*)&sXv[b][qB * 32 + kg * 4 + j][0] = xvv;
            }
            uint4 pk;
            pk.x = pkbf(ya.x, ya.y); pk.y = pkbf(ya.z, ya.w);
            pk.z = pkbf(yb.x, yb.y); pk.w = pkbf(yb.z, yb.w);
            *(uint4*)(a2b + j * 72) = pk;
            const float y[8] = {ya.x, ya.y, ya.z, ya.w, yb.x, yb.y, yb.z, yb.w};
            #pragma unroll
            for (int c = 0; c < 8; ++c) {
                float l = fmaf(y[c], -CL, xqc[c]);
                l = fmaf(-xv0, wp[c*3], l);
                l = fmaf(-xv1, wp[c*3+1], l);
                l = fmaf(-xv2, wp[c*3+2], l);
                float e = EXP2F(l);
                ev[j][c] = e;
                sm[c] += e;
            }
        }
        #pragma unroll
        for (int c = 0; c < 8; ++c) {              // k-sum over kg lanes (bits 3..5)
            float s = sm[c];
            s += __shfl_xor(s, 8);
            s += __shfl_xor(s, 16);
            s += __shfl_xor(s, 32);
            sm[c] = RCPF(s);
        }
        #pragma unroll
        for (int j = 0; j < 4; ++j) {
            uint4 pw;
            pw.x = pkbf(ev[j][0] * sm[0], ev[j][1] * sm[1]);
            pw.y = pkbf(ev[j][2] * sm[2], ev[j][3] * sm[3]);
            pw.z = pkbf(ev[j][4] * sm[4], ev[j][5] * sm[5]);
            pw.w = pkbf(ev[j][6] * sm[6], ev[j][7] * sm[7]);
            *(uint4*)(a1b + j * 72) = pw;
        }
    };

    // ---------------- consumer: MFMA + epilogue + k-max from buffer b ------
    auto consume = [&](int pc, int b) {
        const long n0 = 2L * pc;
        const long n1 = n0 + 1;
        const bool has1 = (n1 < Nq);
        const int cwv = wv - 2;
        #pragma unroll
        for (int g = 0; g < 2; ++g) {
            float m0 = -1e30f, m1 = -1e30f;
            #pragma unroll
            for (int mt = 0; mt < 4; ++mt) {
                floatx4 acc[4];
                #pragma unroll
                for (int ty = 0; ty < 4; ++ty) acc[ty] = (floatx4){0.f, 0.f, 0.f, 0.f};
                const int r0 = mt * 16 + cc;           // A row m = lane&15
                #pragma unroll
                for (int ks = 0; ks < 2; ++ks) {
                    const int kof = ks * 32 + quad * 8; // A k-slice = quad*8+j
                    short8 a1 = *(const short8*)&sA1[b][r0 * 72 + kof];
                    short8 a2 = *(const short8*)&sA2[b][r0 * 72 + kof];
                    acc[0] = __builtin_amdgcn_mfma_f32_16x16x32_bf16(a1, bW[g][0][ks], acc[0], 0, 0, 0);
                    acc[1] = __builtin_amdgcn_mfma_f32_16x16x32_bf16(a1, bW[g][1][ks], acc[1], 0, 0, 0);
                    acc[2] = __builtin_amdgcn_mfma_f32_16x16x32_bf16(a1, bW[g][2][ks], acc[2], 0, 0, 0);
                    acc[3] = __builtin_amdgcn_mfma_f32_16x16x32_bf16(a2, bW[g][3][ks], acc[3], 0, 0, 0);
                }
                // C/D: col = lane&15, row = quad*4 + reg
                #pragma unroll
                for (int reg = 0; reg < 4; ++reg) {
                    const int r = mt * 16 + quad * 4 + reg;
                    float4 xv = *(const float4*)&sXv[b][r][0];
                    float y = acc[0][reg] * xv.x + acc[1][reg] * xv.y + acc[2][reg] * xv.z;
                    float ybn = lrelu(fmaf(y, e1s[g], e1b[g]));
                    float rbn = fmaf(acc[3][reg], ers[g], erb[g]);
                    float v = lrelu(ybn + rbn);
                    if (mt < 2) m0 = fmaxf(m0, v); else m1 = fmaxf(m1, v);
                }
            }
            m0 = fmaxf(m0, __shfl_xor(m0, 16));
            m0 = fmaxf(m0, __shfl_xor(m0, 32));
            m1 = fmaxf(m1, __shfl_xor(m1, 16));
            m1 = fmaxf(m1, __shfl_xor(m1, 32));
            if (lane < 16) {
                const int o = cwv * 32 + g * 16 + cc;
                out[n0 * CO + o] = m0;
                if (has1) out[n1 * CO + o] = m1;
            }
        }
    };

    // ---------------- pipeline ----------------
    if (producer) produce(bid, 0);
    __syncthreads();
    for (int i = 0; i < niter; ++i) {
        const int buf = i & 1;
        if (producer) {
            const int pp = bid + (i + 1) * NBLOCKS;
            if (pp < npair) produce(pp, buf ^ 1);
        } else {
            consume(bid + i * NBLOCKS, buf);
        }
        __syncthreads();   // fill(i+1) done & drain(i) done -> safe to reuse bufs
    }
}

extern "C" void kernel_launch(void* const* d_in, const int* in_sizes, int n_in,
                              void* d_out, int out_size, void* d_ws, size_t ws_size,
                              hipStream_t stream) {
    const float* q_points = (const float*)d_in[0];
    const float* s_points = (const float*)d_in[1];
    const int*   neighb   = (const int*)  d_in[2];
    const float* feat     = (const float*)d_in[3];
    const float* W_pos2   = (const float*)d_in[4];
    const float* W_attn   = (const float*)d_in[5];
    const float* W_res    = (const float*)d_in[6];
    const float* bnq_g = (const float*)d_in[7];
    const float* bnq_b = (const float*)d_in[8];
    const float* bnq_m = (const float*)d_in[9];
    const float* bnq_v = (const float*)d_in[10];
    const float* bnp_g = (const float*)d_in[11];
    const float* bnp_b = (const float*)d_in[12];
    const float* bnp_m = (const float*)d_in[13];
    const float* bnp_v = (const float*)d_in[14];
    const float* bn1_g = (const float*)d_in[15];
    const float* bn1_b = (const float*)d_in[16];
    const float* bn1_m = (const float*)d_in[17];
    const float* bn1_v = (const float*)d_in[18];
    const float* bnr_g = (const float*)d_in[19];
    const float* bnr_b = (const float*)d_in[20];
    const float* bnr_m = (const float*)d_in[21];
    const float* bnr_v = (const float*)d_in[22];
    float* out = (float*)d_out;

    int Nq = in_sizes[0] / 3;               // 20000

    // zero page for shadow-row gathers (d_ws is re-poisoned 0xAA before every
    // timed launch -> must re-zero every call; memset nodes are graph-capturable)
    size_t zn = ws_size < 4096 ? ws_size : (size_t)4096;
    hipMemsetAsync(d_ws, 0, zn, stream);

    hipLaunchKernelGGL(GCT_61272003445298_kernel,
                       dim3(NBLOCKS), dim3(256), 0, stream,
                       q_points, s_points, neighb, feat, W_pos2, W_attn, W_res,
                       bnq_g, bnq_b, bnq_m, bnq_v,
                       bnp_g, bnp_b, bnp_m, bnp_v,
                       bn1_g, bn1_b, bn1_m, bn1_v,
                       bnr_g, bnr_b, bnr_m, bnr_v,
                       (const float*)d_ws, out, Nq);
}

// Round 8
// 172.646 us; speedup vs baseline: 1.1142x; 1.1142x over previous
//
#include <hip/hip_runtime.h>
#include <hip/hip_bf16.h>
#include <math.h>

// Nq=20000, K=32, Cin=3, Fc=64, Co=64. Persistent blocks, 2 queries/iter.
// In-wave pipelined: iter i issues gathers for pair p(i+1) (idx prefetched at
// i-1), consumes pair p(i) via MFMA, then finishes p(i+1) VALU into buf^1.
// One barrier per iteration, double-buffered LDS.
#define KNB 32
#define FC 64
#define CO 64
#define EPS 1e-5f
#define NBLOCKS 768
#define CL 0.180336880095853f   // 0.125 * log2(e): softmax scale folded for exp2

typedef __attribute__((ext_vector_type(8))) short short8;   // 8 bf16 = 4 VGPRs
typedef __attribute__((ext_vector_type(4))) float floatx4;  // MFMA C/D

#if __has_builtin(__builtin_amdgcn_exp2f)
#define EXP2F(x) __builtin_amdgcn_exp2f(x)
#else
#define EXP2F(x) exp2f(x)
#endif
#if __has_builtin(__builtin_amdgcn_rcpf)
#define RCPF(x) __builtin_amdgcn_rcpf(x)
#else
#define RCPF(x) (1.f / (x))
#endif

// native packed f32->bf16 RNE (v_cvt_pk_bf16_f32 on gfx950): 1 inst / 2 values
__device__ __forceinline__ unsigned pk2(float a, float b) {    // a->lo, b->hi
    __hip_bfloat162 h = __float22bfloat162_rn(float2{a, b});
    unsigned u; __builtin_memcpy(&u, &h, 4); return u;
}
__device__ __forceinline__ float lrelu(float x) { return fmaxf(x, 0.1f * x); }

// (256,3): 170-VGPR budget for ~35 staged-load regs; (256,6) spilled in r4.
__global__ __launch_bounds__(256, 3) void GCT_61272003445298_kernel(
    const float* __restrict__ q_points,   // [Nq,3]
    const float* __restrict__ s_points,   // [Nq,3]
    const int*   __restrict__ neighb,     // [Nq,32]
    const float* __restrict__ feat,       // [Nq,64]
    const float* __restrict__ W_pos2,     // [64,3]
    const float* __restrict__ W_attn,     // [192,64]
    const float* __restrict__ W_res,      // [64,64]
    const float* __restrict__ bnq_g, const float* __restrict__ bnq_b,
    const float* __restrict__ bnq_m, const float* __restrict__ bnq_v,
    const float* __restrict__ bnp_g, const float* __restrict__ bnp_b,
    const float* __restrict__ bnp_m, const float* __restrict__ bnp_v,
    const float* __restrict__ bn1_g, const float* __restrict__ bn1_b,
    const float* __restrict__ bn1_m, const float* __restrict__ bn1_v,
    const float* __restrict__ bnr_g, const float* __restrict__ bnr_b,
    const float* __restrict__ bnr_m, const float* __restrict__ bnr_v,
    const float* __restrict__ zp,         // 4KB zero page in d_ws (shadow row)
    float* __restrict__ out, int Nq)
{
    const int t = threadIdx.x;
    const int wv = t >> 6;
    const int lane = t & 63;
    const int bid = blockIdx.x;
    // consumer mapping
    const int cc = lane & 15, quad = lane >> 4;
    const int o = wv * 16 + cc;                 // output channel
    // producer mapping (r6): thread = (qB, kg, fqB)
    const int qB  = t >> 7;                     // query within pair
    const int kg  = lane >> 3;                  // 0..7 -> rows kg*4..+3
    const int fqB = (((t >> 6) & 1) << 3) + (lane & 7);   // 0..15, 4 f each

    // rows m = q*32 + k; pitch 72 shorts = 144 B (16B-aligned b128)
    __shared__ __align__(16) short sA1[2][64 * 72];   // softmax probs
    __shared__ __align__(16) short sA2[2][64 * 72];   // gathered yg
    __shared__ __align__(16) float sXv[2][64][4];     // x_v per row
    __shared__ __align__(16) float sWp2[192];         // CL * W_pos2
    __shared__ __align__(16) float sQs[64], sQb[64];  // bnq folded

    // ---------------- one-time init ----------------
    if (t < 192) sWp2[t] = CL * W_pos2[t];
    if (t < 64) {
        float sc = bnq_g[t] * rsqrtf(bnq_v[t] + EPS);
        sQs[t] = sc; sQb[t] = bnq_b[t] - bnq_m[t] * sc;
    }
    const float ps0 = bnp_g[0] * rsqrtf(bnp_v[0] + EPS);
    const float ps1 = bnp_g[1] * rsqrtf(bnp_v[1] + EPS);
    const float ps2 = bnp_g[2] * rsqrtf(bnp_v[2] + EPS);
    const float pb0 = bnp_b[0] - bnp_m[0] * ps0;
    const float pb1 = bnp_b[1] - bnp_m[1] * ps1;
    const float pb2 = bnp_b[2] - bnp_m[2] * ps2;
    // epilogue BN (per-lane o): scales folded into bW below; biases kept
    const float e1s = bn1_g[o] * rsqrtf(bn1_v[o] + EPS);
    const float e1b = bn1_b[o] - bn1_m[o] * e1s;
    const float ers = bnr_g[o] * rsqrtf(bnr_v[o] + EPS);
    const float erb = bnr_b[o] - bnr_m[o] * ers;

    // persistent bf16 weights, BN scale pre-folded (ty<3: *e1s, ty3: *ers)
    short8 bW[4][2];
    #pragma unroll
    for (int ty = 0; ty < 4; ++ty) {
        const float* wrow = (ty < 3) ? (W_attn + (long)(o * 3 + ty) * FC)
                                     : (W_res  + (long)o * FC);
        const float sc = (ty < 3) ? e1s : ers;
        #pragma unroll
        for (int ks = 0; ks < 2; ++ks) {
            int k0 = ks * 32 + quad * 8;
            float4 w0 = *(const float4*)(wrow + k0);
            float4 w1 = *(const float4*)(wrow + k0 + 4);
            uint4 pv;
            pv.x = pk2(w0.x * sc, w0.y * sc);
            pv.y = pk2(w0.z * sc, w0.w * sc);
            pv.z = pk2(w1.x * sc, w1.y * sc);
            pv.w = pk2(w1.z * sc, w1.w * sc);
            __builtin_memcpy(&bW[ty][ks], &pv, 16);
        }
    }
    __syncthreads();

    // persistent pos-weight slice for this thread's 4 f (CL-prescaled)
    float wp[12];
    *(float4*)&wp[0] = *(const float4*)&sWp2[fqB * 12];
    *(float4*)&wp[4] = *(const float4*)&sWp2[fqB * 12 + 4];
    *(float4*)&wp[8] = *(const float4*)&sWp2[fqB * 12 + 8];
    const float4 qs4 = *(const float4*)&sQs[fqB * 4];
    const float4 qb4 = *(const float4*)&sQb[fqB * 4];

    const int npair = (Nq + 1) >> 1;
    const int niter = (npair - bid + NBLOCKS - 1) / NBLOCKS;

    // ---- staging registers (live across consume) ----
    int4  idxCur, idxNext;
    float4 gF[4];                    // gathered feat chunk per row j
    float  gS0[4], gS1[4], gS2[4];   // gathered s_points per row j
    float4 oF;                       // own feat chunk (xqc)
    float  oQ0, oQ1, oQ2, oS0, oS1, oS2;

    auto loadNb = [&](int pr) -> int4 {
        return *(const int4*)(neighb + (long)(2 * pr + qB) * KNB + kg * 4);
    };
    auto issueGathers = [&](int pr, int4 idx4) {
        const long nn = 2L * pr + qB;
        oQ0 = q_points[nn * 3 + 0]; oQ1 = q_points[nn * 3 + 1]; oQ2 = q_points[nn * 3 + 2];
        oS0 = s_points[nn * 3 + 0]; oS1 = s_points[nn * 3 + 1]; oS2 = s_points[nn * 3 + 2];
        oF  = *(const float4*)(feat + nn * FC + fqB * 4);
        #pragma unroll
        for (int j = 0; j < 4; ++j) {
            const int idx = ((const int*)&idx4)[j];
            const bool valid = (idx < Nq);          // idx==Nq -> shadow zero row
            const float* fb = valid ? (feat + (long)idx * FC) : zp;
            const float* sb = valid ? (s_points + (long)idx * 3) : zp;
            gF[j] = *(const float4*)(fb + fqB * 4);
            gS0[j] = sb[0]; gS1[j] = sb[1]; gS2[j] = sb[2];
        }
    };
    auto computeProduce = [&](int b) {
        const float pp0 = lrelu(fmaf(oS0, ps0, pb0));
        const float pp1 = lrelu(fmaf(oS1, ps1, pb1));
        const float pp2 = lrelu(fmaf(oS2, ps2, pb2));
        float xqc[4];
        {
            const float fx[4] = {oF.x, oF.y, oF.z, oF.w};
            const float qs[4] = {qs4.x, qs4.y, qs4.z, qs4.w};
            const float qb[4] = {qb4.x, qb4.y, qb4.z, qb4.w};
            #pragma unroll
            for (int c = 0; c < 4; ++c) {
                float xq = lrelu(fmaf(fx[c], qs[c], qb[c]));
                xqc[c] = fmaf(pp0, wp[c*3], fmaf(pp1, wp[c*3+1],
                              fmaf(pp2, wp[c*3+2], CL * xq)));
            }
        }
        short* a1b = &sA1[b][(qB * 32 + kg * 4) * 72 + fqB * 4];
        short* a2b = &sA2[b][(qB * 32 + kg * 4) * 72 + fqB * 4];
        float ev[4][4];
        float s0 = 0.f, s1 = 0.f, s2 = 0.f, s3 = 0.f;
        #pragma unroll
        for (int j = 0; j < 4; ++j) {
            const float xv0 = gS0[j] - oQ0;
            const float xv1 = gS1[j] - oQ1;
            const float xv2 = gS2[j] - oQ2;
            if (fqB == 0) {
                float4 xvv = {xv0, xv1, xv2, 0.f};
                *(float4*)&sXv[b][qB * 32 + kg * 4 + j][0] = xvv;
            }
            const float4 y = gF[j];
            uint2 pk; pk.x = pk2(y.x, y.y); pk.y = pk2(y.z, y.w);
            *(uint2*)(a2b + j * 72) = pk;
            float l0 = fmaf(y.x, -CL, xqc[0]);
            l0 = fmaf(-xv0, wp[0], l0); l0 = fmaf(-xv1, wp[1], l0); l0 = fmaf(-xv2, wp[2], l0);
            float l1 = fmaf(y.y, -CL, xqc[1]);
            l1 = fmaf(-xv0, wp[3], l1); l1 = fmaf(-xv1, wp[4], l1); l1 = fmaf(-xv2, wp[5], l1);
            float l2 = fmaf(y.z, -CL, xqc[2]);
            l2 = fmaf(-xv0, wp[6], l2); l2 = fmaf(-xv1, wp[7], l2); l2 = fmaf(-xv2, wp[8], l2);
            float l3 = fmaf(y.w, -CL, xqc[3]);
            l3 = fmaf(-xv0, wp[9], l3); l3 = fmaf(-xv1, wp[10], l3); l3 = fmaf(-xv2, wp[11], l3);
            ev[j][0] = EXP2F(l0); ev[j][1] = EXP2F(l1);
            ev[j][2] = EXP2F(l2); ev[j][3] = EXP2F(l3);
            s0 += ev[j][0]; s1 += ev[j][1]; s2 += ev[j][2]; s3 += ev[j][3];
        }
        s0 += __shfl_xor(s0, 8); s0 += __shfl_xor(s0, 16); s0 += __shfl_xor(s0, 32);
        s1 += __shfl_xor(s1, 8); s1 += __shfl_xor(s1, 16); s1 += __shfl_xor(s1, 32);
        s2 += __shfl_xor(s2, 8); s2 += __shfl_xor(s2, 16); s2 += __shfl_xor(s2, 32);
        s3 += __shfl_xor(s3, 8); s3 += __shfl_xor(s3, 16); s3 += __shfl_xor(s3, 32);
        const float i0 = RCPF(s0), i1 = RCPF(s1), i2 = RCPF(s2), i3 = RCPF(s3);
        #pragma unroll
        for (int j = 0; j < 4; ++j) {
            uint2 pw;
            pw.x = pk2(ev[j][0] * i0, ev[j][1] * i1);
            pw.y = pk2(ev[j][2] * i2, ev[j][3] * i3);
            *(uint2*)(a1b + j * 72) = pw;
        }
    };
    auto consume = [&](int pc, int b) {
        const long n0 = 2L * pc;
        const long n1 = n0 + 1;
        const bool has1 = (n1 < Nq);
        float m0 = -1e30f, m1 = -1e30f;
        #pragma unroll
        for (int mt = 0; mt < 4; ++mt) {
            floatx4 acc[4];
            #pragma unroll
            for (int ty = 0; ty < 4; ++ty) acc[ty] = (floatx4){0.f, 0.f, 0.f, 0.f};
            const int r0 = mt * 16 + cc;               // A row m = lane&15
            #pragma unroll
            for (int ks = 0; ks < 2; ++ks) {
                const int kof = ks * 32 + quad * 8;    // A k-slice = quad*8+j
                short8 a1 = *(const short8*)&sA1[b][r0 * 72 + kof];
                short8 a2 = *(const short8*)&sA2[b][r0 * 72 + kof];
                acc[0] = __builtin_amdgcn_mfma_f32_16x16x32_bf16(a1, bW[0][ks], acc[0], 0, 0, 0);
                acc[1] = __builtin_amdgcn_mfma_f32_16x16x32_bf16(a1, bW[1][ks], acc[1], 0, 0, 0);
                acc[2] = __builtin_amdgcn_mfma_f32_16x16x32_bf16(a1, bW[2][ks], acc[2], 0, 0, 0);
                acc[3] = __builtin_amdgcn_mfma_f32_16x16x32_bf16(a2, bW[3][ks], acc[3], 0, 0, 0);
            }
            // C/D: col = lane&15, row = quad*4 + reg. BN scales already in bW;
            // outer lrelu and +erb deferred past k-max (lrelu monotone).
            #pragma unroll
            for (int reg = 0; reg < 4; ++reg) {
                const int r = mt * 16 + quad * 4 + reg;
                float4 xv = *(const float4*)&sXv[b][r][0];
                float y = acc[0][reg] * xv.x + acc[1][reg] * xv.y + acc[2][reg] * xv.z;
                float v = lrelu(y + e1b) + acc[3][reg];
                if (mt < 2) m0 = fmaxf(m0, v); else m1 = fmaxf(m1, v);
            }
        }
        m0 = fmaxf(m0, __shfl_xor(m0, 16));
        m0 = fmaxf(m0, __shfl_xor(m0, 32));
        m1 = fmaxf(m1, __shfl_xor(m1, 16));
        m1 = fmaxf(m1, __shfl_xor(m1, 32));
        if (lane < 16) {
            out[n0 * CO + o] = lrelu(m0 + erb);
            if (has1) out[n1 * CO + o] = lrelu(m1 + erb);
        }
    };

    // ---------------- pipelined main loop ----------------
    idxCur = loadNb(bid);
    if (bid + NBLOCKS < npair) idxNext = loadNb(bid + NBLOCKS);
    issueGathers(bid, idxCur);
    computeProduce(0);
    __syncthreads();
    for (int i = 0; i < niter; ++i) {
        const int buf = i & 1;
        const int pp1 = bid + (i + 1) * NBLOCKS;
        const int pp2 = bid + (i + 2) * NBLOCKS;
        if (pp1 < npair) {
            issueGathers(pp1, idxNext);        // VMEM in flight across consume
            if (pp2 < npair) idxNext = loadNb(pp2);
        }
        consume(bid + i * NBLOCKS, buf);
        if (pp1 < npair) computeProduce(buf ^ 1);
        __syncthreads();   // next-buf filled & this-buf drained
    }
}

extern "C" void kernel_launch(void* const* d_in, const int* in_sizes, int n_in,
                              void* d_out, int out_size, void* d_ws, size_t ws_size,
                              hipStream_t stream) {
    const float* q_points = (const float*)d_in[0];
    const float* s_points = (const float*)d_in[1];
    const int*   neighb   = (const int*)  d_in[2];
    const float* feat     = (const float*)d_in[3];
    const float* W_pos2   = (const float*)d_in[4];
    const float* W_attn   = (const float*)d_in[5];
    const float* W_res    = (const float*)d_in[6];
    const float* bnq_g = (const float*)d_in[7];
    const float* bnq_b = (const float*)d_in[8];
    const float* bnq_m = (const float*)d_in[9];
    const float* bnq_v = (const float*)d_in[10];
    const float* bnp_g = (const float*)d_in[11];
    const float* bnp_b = (const float*)d_in[12];
    const float* bnp_m = (const float*)d_in[13];
    const float* bnp_v = (const float*)d_in[14];
    const float* bn1_g = (const float*)d_in[15];
    const float* bn1_b = (const float*)d_in[16];
    const float* bn1_m = (const float*)d_in[17];
    const float* bn1_v = (const float*)d_in[18];
    const float* bnr_g = (const float*)d_in[19];
    const float* bnr_b = (const float*)d_in[20];
    const float* bnr_m = (const float*)d_in[21];
    const float* bnr_v = (const float*)d_in[22];
    float* out = (float*)d_out;

    int Nq = in_sizes[0] / 3;               // 20000

    // zero page for shadow-row gathers; d_ws re-poisoned every timed call
    size_t zn = ws_size < 4096 ? ws_size : (size_t)4096;
    hipMemsetAsync(d_ws, 0, zn, stream);

    hipLaunchKernelGGL(GCT_61272003445298_kernel,
                       dim3(NBLOCKS), dim3(256), 0, stream,
                       q_points, s_points, neighb, feat, W_pos2, W_attn, W_res,
                       bnq_g, bnq_b, bnq_m, bnq_v,
                       bnp_g, bnp_b, bnp_m, bnp_v,
                       bn1_g, bn1_b, bn1_m, bn1_v,
                       bnr_g, bnr_b, bnr_m, bnr_v,
                       (const float*)d_ws, out, Nq);
}